// Round 5
// baseline (2968.119 us; speedup 1.0000x reference)
//
#include <hip/hip_runtime.h>
#include <hip/hip_cooperative_groups.h>
#include <math.h>

namespace cg = cooperative_groups;

#define F_IN 512
#define HD 64
#define CD 16
#define K_HOPS 10
#define PAD 68

#define BKT_SHIFT 7
#define BKT_NODES 128
#define NBKT_MAX 1024
#define EPB 8192

#define COOP_BLOCKS 1024

typedef unsigned int uint32;

static __device__ __forceinline__ float bf2f(unsigned short h) {
    return __uint_as_float(((uint32)h) << 16);
}
static __device__ __forceinline__ unsigned short f2bf(float x) {
    uint32 u = __float_as_uint(x);
    u = (u + 0x7FFFu + ((u >> 16) & 1u)) >> 16;   // RNE
    return (unsigned short)u;
}

// ---------------- CSR build: two-level bucket sort ----------------

__global__ void zero_kernel(int* __restrict__ p, int n) {
    int i = blockIdx.x * blockDim.x + threadIdx.x;
    if (i < n) p[i] = 0;
}

__global__ __launch_bounds__(256) void bucket_hist_kernel(
    const int* __restrict__ cols, int* __restrict__ bcnt, int e, int nb) {
    __shared__ int c[NBKT_MAX];
    int t = threadIdx.x;
    for (int i = t; i < nb; i += 256) c[i] = 0;
    __syncthreads();
    int base = blockIdx.x * EPB;
    int end = min(base + EPB, e);
    for (int i = base + t; i < end; i += 256)
        atomicAdd(&c[cols[i] >> BKT_SHIFT], 1);
    __syncthreads();
    for (int i = t; i < nb; i += 256)
        if (c[i]) atomicAdd(&bcnt[i], c[i]);
}

__global__ __launch_bounds__(256) void bucket_scan_kernel(
    const int* __restrict__ bcnt, int* __restrict__ bstart,
    int* __restrict__ bcur, int nb) {
    __shared__ int s[256];
    int t = threadIdx.x;
    int v[4]; int sum = 0;
#pragma unroll
    for (int i = 0; i < 4; ++i) {
        int idx = t * 4 + i;
        v[i] = (idx < nb) ? bcnt[idx] : 0;
        sum += v[i];
    }
    s[t] = sum; __syncthreads();
    for (int off = 1; off < 256; off <<= 1) {
        int x = (t >= off) ? s[t - off] : 0;
        __syncthreads();
        s[t] += x;
        __syncthreads();
    }
    int excl = s[t] - sum;
#pragma unroll
    for (int i = 0; i < 4; ++i) {
        int idx = t * 4 + i;
        if (idx < nb) { bstart[idx] = excl; bcur[idx] = excl; }
        excl += v[i];
    }
    if (t == 255) bstart[nb] = excl;
}

__global__ __launch_bounds__(256) void scatter_bin_kernel(
    const int* __restrict__ rows, const int* __restrict__ cols,
    int* __restrict__ bcur, uint32* __restrict__ stage, int e, int nb) {
    __shared__ int c[NBKT_MAX];
    int t = threadIdx.x;
    for (int i = t; i < nb; i += 256) c[i] = 0;
    __syncthreads();
    int base = blockIdx.x * EPB;
    int end = min(base + EPB, e);
    for (int i = base + t; i < end; i += 256)
        atomicAdd(&c[cols[i] >> BKT_SHIFT], 1);
    __syncthreads();
    for (int i = t; i < nb; i += 256) {
        int cc = c[i];
        if (cc) c[i] = atomicAdd(&bcur[i], cc);
    }
    __syncthreads();
    for (int i = base + t; i < end; i += 256) {
        int col = cols[i];
        int b = col >> BKT_SHIFT;
        int pos = atomicAdd(&c[b], 1);
        stage[pos] = ((uint32)rows[i] << BKT_SHIFT) | (uint32)(col & (BKT_NODES - 1));
    }
}

__global__ __launch_bounds__(256) void bucket_sort_kernel(
    const uint32* __restrict__ stage, const int* __restrict__ bstart,
    int* __restrict__ rowstart, float* __restrict__ dis,
    int* __restrict__ csr, int n, int e) {
    __shared__ int cnt[BKT_NODES];
    __shared__ int excl[BKT_NODES];
    __shared__ int lcur[BKT_NODES];
    int b = blockIdx.x, t = threadIdx.x;
    int s0 = bstart[b], s1 = bstart[b + 1];
    int nnode = min(BKT_NODES, n - b * BKT_NODES);
    if (t < BKT_NODES) cnt[t] = 0;
    __syncthreads();
    for (int i = s0 + t; i < s1; i += 256)
        atomicAdd(&cnt[stage[i] & (BKT_NODES - 1)], 1);
    __syncthreads();
    if (t < BKT_NODES) excl[t] = cnt[t];
    __syncthreads();
    for (int off = 1; off < BKT_NODES; off <<= 1) {
        int x = 0;
        if (t < BKT_NODES && t >= off) x = excl[t - off];
        __syncthreads();
        if (t < BKT_NODES) excl[t] += x;
        __syncthreads();
    }
    if (t < BKT_NODES) {
        int rs = s0 + excl[t] - cnt[t];
        lcur[t] = rs;
        if (t < nnode) {
            rowstart[b * BKT_NODES + t] = rs;
            dis[b * BKT_NODES + t] = rsqrtf((float)(cnt[t] + 1));
        }
    }
    if (b == 0 && t == 0) rowstart[n] = e;
    __syncthreads();
    for (int i = s0 + t; i < s1; i += 256) {
        uint32 v = stage[i];
        int pos = atomicAdd(&lcur[v & (BKT_NODES - 1)], 1);
        csr[pos] = (int)(v >> BKT_SHIFT);
    }
}

// ---------------- fused MLP + riemann + init ----------------

__global__ __launch_bounds__(256) void mlp_kernel(
    const float* __restrict__ x, const float* __restrict__ W1,
    const float* __restrict__ b1, const float* __restrict__ W2,
    const float* __restrict__ b2, const float* __restrict__ dis,
    const float* __restrict__ temp, const float* __restrict__ w_for_norm,
    unsigned short* __restrict__ g0, float* __restrict__ hidden, int n) {
    __shared__ float xt[64][PAD];
    __shared__ float w1s[64][PAD];
    __shared__ float w2s[64][16];

    const int t = threadIdx.x;
    const int row0 = blockIdx.x * 64;

    {
        float4 v = *(const float4*)(W2 + t * 4);
        *(float4*)&w2s[t >> 2][(t & 3) * 4] = v;
    }

    const int tr = t >> 4, th = t & 15;
    float acc[4][4];
#pragma unroll
    for (int i = 0; i < 4; ++i)
#pragma unroll
        for (int j = 0; j < 4; ++j) acc[i][j] = 0.0f;

    for (int c = 0; c < F_IN / 64; ++c) {
        __syncthreads();
        {
            const int k4 = t & 15, rl = t >> 4;
            const int swz = 4 * (k4 & 7);
#pragma unroll
            for (int it = 0; it < 4; ++it) {
                int row = rl + 16 * it;
                int gr = row0 + row; if (gr >= n) gr = n - 1;
                float4 v = *(const float4*)(x + (long)gr * F_IN + c * 64 + k4 * 4);
                xt[k4 * 4 + 0][row ^ swz] = v.x;
                xt[k4 * 4 + 1][row ^ swz] = v.y;
                xt[k4 * 4 + 2][row ^ swz] = v.z;
                xt[k4 * 4 + 3][row ^ swz] = v.w;
            }
            const int h4 = t & 15, kl = t >> 4;
#pragma unroll
            for (int it = 0; it < 4; ++it) {
                int kk = kl + 16 * it;
                float4 v = *(const float4*)(W1 + (long)(c * 64 + kk) * HD + h4 * 4);
                *(float4*)&w1s[kk][h4 * 4] = v;
            }
        }
        __syncthreads();
#pragma unroll 8
        for (int kk = 0; kk < 64; ++kk) {
            float4 xv = *(const float4*)&xt[kk][(tr * 4) ^ (4 * ((kk >> 2) & 7))];
            float4 wv = *(const float4*)&w1s[kk][th * 4];
            acc[0][0] = fmaf(xv.x, wv.x, acc[0][0]);
            acc[0][1] = fmaf(xv.x, wv.y, acc[0][1]);
            acc[0][2] = fmaf(xv.x, wv.z, acc[0][2]);
            acc[0][3] = fmaf(xv.x, wv.w, acc[0][3]);
            acc[1][0] = fmaf(xv.y, wv.x, acc[1][0]);
            acc[1][1] = fmaf(xv.y, wv.y, acc[1][1]);
            acc[1][2] = fmaf(xv.y, wv.z, acc[1][2]);
            acc[1][3] = fmaf(xv.y, wv.w, acc[1][3]);
            acc[2][0] = fmaf(xv.z, wv.x, acc[2][0]);
            acc[2][1] = fmaf(xv.z, wv.y, acc[2][1]);
            acc[2][2] = fmaf(xv.z, wv.z, acc[2][2]);
            acc[2][3] = fmaf(xv.z, wv.w, acc[2][3]);
            acc[3][0] = fmaf(xv.w, wv.x, acc[3][0]);
            acc[3][1] = fmaf(xv.w, wv.y, acc[3][1]);
            acc[3][2] = fmaf(xv.w, wv.z, acc[3][2]);
            acc[3][3] = fmaf(xv.w, wv.w, acc[3][3]);
        }
    }

    __syncthreads();
    {
        float4 bv = *(const float4*)(b1 + th * 4);
        float bb[4] = {bv.x, bv.y, bv.z, bv.w};
#pragma unroll
        for (int i = 0; i < 4; ++i) {
            float4 hv;
            hv.x = acc[i][0] + bb[0]; hv.x = hv.x > 0.f ? hv.x : 0.f;
            hv.y = acc[i][1] + bb[1]; hv.y = hv.y > 0.f ? hv.y : 0.f;
            hv.z = acc[i][2] + bb[2]; hv.z = hv.z > 0.f ? hv.z : 0.f;
            hv.w = acc[i][3] + bb[3]; hv.w = hv.w > 0.f ? hv.w : 0.f;
            *(float4*)&xt[tr * 4 + i][th * 4] = hv;
        }
    }
    __syncthreads();

    {
        const int r = t >> 2, oq = t & 3;
        float4 b2v = *(const float4*)(b2 + oq * 4);
        float o[4] = {b2v.x, b2v.y, b2v.z, b2v.w};
#pragma unroll 8
        for (int k = 0; k < HD; ++k) {
            float hv = xt[r][k];
            float4 wv = *(const float4*)&w2s[k][oq * 4];
            o[0] = fmaf(hv, wv.x, o[0]);
            o[1] = fmaf(hv, wv.y, o[1]);
            o[2] = fmaf(hv, wv.z, o[2]);
            o[3] = fmaf(hv, wv.w, o[3]);
        }
        float4 wn = *(const float4*)(w_for_norm + oq * 4);
        float p = o[0] * o[0] * fabsf(wn.x) + o[1] * o[1] * fabsf(wn.y) +
                  o[2] * o[2] * fabsf(wn.z) + o[3] * o[3] * fabsf(wn.w);
        p += __shfl_xor(p, 1);
        p += __shfl_xor(p, 2);
        float inv = 1.0f / (sqrtf(p + 0.01f) + 0.01f);
        int grow = row0 + r;
        if (grow < n) {
            float t0 = temp[0];
            float d = dis[grow];
            float hn0 = o[0] * inv, hn1 = o[1] * inv, hn2 = o[2] * inv, hn3 = o[3] * inv;
            *(float4*)(hidden + (long)grow * CD + oq * 4) =
                make_float4(t0 * hn0, t0 * hn1, t0 * hn2, t0 * hn3);
            ushort4 ov;
            ov.x = f2bf(d * hn0); ov.y = f2bf(d * hn1);
            ov.z = f2bf(d * hn2); ov.w = f2bf(d * hn3);
            *(ushort4*)(g0 + (long)grow * CD + oq * 4) = ov;
        }
    }
}

// ---------------- all K hops in one persistent cooperative kernel --------
// Wave owns a contiguous node chunk: rowstart chains (1 load/node), csr
// streams sequentially, g/csr stay warm in per-XCD L2 across hops.
// 16 edge-slots x 4 feat-lanes per wave; grid.sync() between hops.

__global__ __launch_bounds__(256) void hops_kernel(
    unsigned short* __restrict__ gA, unsigned short* __restrict__ gB,
    float* __restrict__ hidden, const float* __restrict__ dis,
    const int* __restrict__ rowstart, const int* __restrict__ csr,
    const float* __restrict__ temp, const float* __restrict__ wfn, int n) {
    cg::grid_group grid = cg::this_grid();

    const int wv = (blockIdx.x << 2) + (threadIdx.x >> 6);
    const int nw = gridDim.x << 2;
    const int lane = threadIdx.x & 63;
    const int slot = lane >> 2, fl = lane & 3;
    const int chunk = (n + nw - 1) / nw;
    const int c0 = min(wv * chunk, n);
    const int c1 = min(c0 + chunk, n);

    const float4 wq = *(const float4*)(wfn + (fl << 2));
    const float wx = fabsf(wq.x), wy = fabsf(wq.y),
                wz = fabsf(wq.z), ww = fabsf(wq.w);

    for (int k = 1; k <= K_HOPS; ++k) {
        const unsigned short* __restrict__ g = (k & 1) ? gA : gB;
        unsigned short* __restrict__ gn = (k & 1) ? gB : gA;
        const float tk = temp[k];
        const int writeg = (k < K_HOPS);

        int rs0 = (c0 < c1) ? rowstart[c0] : 0;
        for (int node = c0; node < c1; ++node) {
            int rs1 = rowstart[node + 1];
            float d = dis[node];
            ushort4 sv = *(const ushort4*)(g + ((long)node << 4) + (fl << 2));

            float a0 = 0.f, a1 = 0.f, a2 = 0.f, a3 = 0.f;
            int e = rs0 + slot;
            while (e + 16 < rs1) {
                int s1 = csr[e];
                int s2 = csr[e + 16];
                ushort4 v1 = *(const ushort4*)(g + ((long)s1 << 4) + (fl << 2));
                ushort4 v2 = *(const ushort4*)(g + ((long)s2 << 4) + (fl << 2));
                a0 += bf2f(v1.x); a1 += bf2f(v1.y);
                a2 += bf2f(v1.z); a3 += bf2f(v1.w);
                a0 += bf2f(v2.x); a1 += bf2f(v2.y);
                a2 += bf2f(v2.z); a3 += bf2f(v2.w);
                e += 32;
            }
            if (e < rs1) {
                int s1 = csr[e];
                ushort4 v1 = *(const ushort4*)(g + ((long)s1 << 4) + (fl << 2));
                a0 += bf2f(v1.x); a1 += bf2f(v1.y);
                a2 += bf2f(v1.z); a3 += bf2f(v1.w);
            }

#pragma unroll
            for (int off = 4; off < 64; off <<= 1) {
                a0 += __shfl_xor(a0, off);
                a1 += __shfl_xor(a1, off);
                a2 += __shfl_xor(a2, off);
                a3 += __shfl_xor(a3, off);
            }

            a0 = (a0 + bf2f(sv.x)) * d;
            a1 = (a1 + bf2f(sv.y)) * d;
            a2 = (a2 + bf2f(sv.z)) * d;
            a3 = (a3 + bf2f(sv.w)) * d;

            float p = a0 * a0 * wx + a1 * a1 * wy + a2 * a2 * wz + a3 * a3 * ww;
            p += __shfl_xor(p, 1);
            p += __shfl_xor(p, 2);
            float inv = 1.0f / (sqrtf(p + 0.01f) + 0.01f);
            float h0 = a0 * inv, h1 = a1 * inv, h2 = a2 * inv, h3 = a3 * inv;

            if (slot == 0) {
                long base = ((long)node << 4) + (fl << 2);
                float4* hp = (float4*)(hidden + base);
                float4 hv = *hp;
                hv.x = fmaf(tk, h0, hv.x);
                hv.y = fmaf(tk, h1, hv.y);
                hv.z = fmaf(tk, h2, hv.z);
                hv.w = fmaf(tk, h3, hv.w);
                *hp = hv;
                if (writeg) {
                    ushort4 o;
                    o.x = f2bf(d * h0); o.y = f2bf(d * h1);
                    o.z = f2bf(d * h2); o.w = f2bf(d * h3);
                    *(ushort4*)(gn + base) = o;
                }
            }
            rs0 = rs1;
        }

        __threadfence();   // device-scope release of g/hidden writes
        grid.sync();       // grid barrier (+acquire) before next hop
    }
}

// ---------------- launch ----------------

static inline long align4up(long w) { return (w + 3) & ~3L; }

extern "C" void kernel_launch(void* const* d_in, const int* in_sizes, int n_in,
                              void* d_out, int out_size, void* d_ws, size_t ws_size,
                              hipStream_t stream) {
    const float* x          = (const float*)d_in[0];
    const int*   edge_index = (const int*)d_in[1];
    const float* W1         = (const float*)d_in[2];
    const float* b1         = (const float*)d_in[3];
    const float* W2         = (const float*)d_in[4];
    const float* b2         = (const float*)d_in[5];
    const float* temp       = (const float*)d_in[6];
    const float* w_for_norm = (const float*)d_in[7];
    float* hidden = (float*)d_out;

    const int n = in_sizes[0] / F_IN;
    const int e = in_sizes[1] / 2;
    const int* rows = edge_index;        // sources
    const int* cols = edge_index + e;    // destinations
    const int nb = (n + BKT_NODES - 1) / BKT_NODES;

    long off = 0;
    int* wsI = (int*)d_ws;
    int* bcnt      = wsI + off; off = align4up(off + NBKT_MAX);
    int* bstart    = wsI + off; off = align4up(off + NBKT_MAX + 1);
    int* bcur      = wsI + off; off = align4up(off + NBKT_MAX);
    int* rowstart  = wsI + off; off = align4up(off + n + 1);
    float* dis     = (float*)(wsI + off); off = align4up(off + n);
    uint32* stage  = (uint32*)(wsI + off); off = align4up(off + e);
    int* csr       = wsI + off; off = align4up(off + e);
    unsigned short* gA = (unsigned short*)(wsI + off); off = align4up(off + n * 8);
    unsigned short* gB = (unsigned short*)(wsI + off); off = align4up(off + n * 8);

    const int B = 256;
    const int nbC = (e + EPB - 1) / EPB;

    zero_kernel<<<(nb + B - 1) / B, B, 0, stream>>>(bcnt, nb);
    bucket_hist_kernel<<<nbC, B, 0, stream>>>(cols, bcnt, e, nb);
    bucket_scan_kernel<<<1, B, 0, stream>>>(bcnt, bstart, bcur, nb);
    scatter_bin_kernel<<<nbC, B, 0, stream>>>(rows, cols, bcur, stage, e, nb);
    bucket_sort_kernel<<<nb, B, 0, stream>>>(stage, bstart, rowstart, dis, csr, n, e);

    mlp_kernel<<<(n + 63) / 64, B, 0, stream>>>(x, W1, b1, W2, b2, dis, temp,
                                                w_for_norm, gA, hidden, n);

    {
        unsigned short* gA_ = gA;
        unsigned short* gB_ = gB;
        float* hidden_ = hidden;
        const float* dis_ = dis;
        const int* rowstart_ = rowstart;
        const int* csr_ = csr;
        const float* temp_ = temp;
        const float* wfn_ = w_for_norm;
        int n_ = n;
        void* args[] = {&gA_, &gB_, &hidden_, &dis_, &rowstart_, &csr_,
                        &temp_, &wfn_, &n_};
        hipLaunchCooperativeKernel((const void*)hops_kernel,
                                   dim3(COOP_BLOCKS), dim3(B), args, 0, stream);
    }
}

// Round 6
// 560.686 us; speedup vs baseline: 5.2937x; 5.2937x over previous
//
#include <hip/hip_runtime.h>
#include <math.h>

#define F_IN 512
#define HD 64
#define CD 16
#define K_HOPS 10

#define BKT_SHIFT 7
#define BKT_NODES 128
#define NBKT_MAX 1024
#define EPB 8192

typedef unsigned int uint32;
typedef __attribute__((ext_vector_type(8))) short short8v;
typedef __attribute__((ext_vector_type(4))) float float4v;

static __device__ __forceinline__ float bf2f(unsigned short h) {
    return __uint_as_float(((uint32)h) << 16);
}
static __device__ __forceinline__ unsigned short f2bf(float x) {
    uint32 u = __float_as_uint(x);
    u = (u + 0x7FFFu + ((u >> 16) & 1u)) >> 16;   // RNE
    return (unsigned short)u;
}

// ---------------- CSR build: two-level bucket sort ----------------

__global__ void zero_kernel(int* __restrict__ p, int n) {
    int i = blockIdx.x * blockDim.x + threadIdx.x;
    if (i < n) p[i] = 0;
}

__global__ __launch_bounds__(256) void bucket_hist_kernel(
    const int* __restrict__ cols, int* __restrict__ bcnt, int e, int nb) {
    __shared__ int c[NBKT_MAX];
    int t = threadIdx.x;
    for (int i = t; i < nb; i += 256) c[i] = 0;
    __syncthreads();
    int base = blockIdx.x * EPB;
    int end = min(base + EPB, e);
    for (int i = base + t; i < end; i += 256)
        atomicAdd(&c[cols[i] >> BKT_SHIFT], 1);
    __syncthreads();
    for (int i = t; i < nb; i += 256)
        if (c[i]) atomicAdd(&bcnt[i], c[i]);
}

__global__ __launch_bounds__(256) void bucket_scan_kernel(
    const int* __restrict__ bcnt, int* __restrict__ bstart,
    int* __restrict__ bcur, int nb) {
    __shared__ int s[256];
    int t = threadIdx.x;
    int v[4]; int sum = 0;
#pragma unroll
    for (int i = 0; i < 4; ++i) {
        int idx = t * 4 + i;
        v[i] = (idx < nb) ? bcnt[idx] : 0;
        sum += v[i];
    }
    s[t] = sum; __syncthreads();
    for (int off = 1; off < 256; off <<= 1) {
        int x = (t >= off) ? s[t - off] : 0;
        __syncthreads();
        s[t] += x;
        __syncthreads();
    }
    int excl = s[t] - sum;
#pragma unroll
    for (int i = 0; i < 4; ++i) {
        int idx = t * 4 + i;
        if (idx < nb) { bstart[idx] = excl; bcur[idx] = excl; }
        excl += v[i];
    }
    if (t == 255) bstart[nb] = excl;
}

__global__ __launch_bounds__(256) void scatter_bin_kernel(
    const int* __restrict__ rows, const int* __restrict__ cols,
    int* __restrict__ bcur, uint32* __restrict__ stage, int e, int nb) {
    __shared__ int c[NBKT_MAX];
    int t = threadIdx.x;
    for (int i = t; i < nb; i += 256) c[i] = 0;
    __syncthreads();
    int base = blockIdx.x * EPB;
    int end = min(base + EPB, e);
    for (int i = base + t; i < end; i += 256)
        atomicAdd(&c[cols[i] >> BKT_SHIFT], 1);
    __syncthreads();
    for (int i = t; i < nb; i += 256) {
        int cc = c[i];
        if (cc) c[i] = atomicAdd(&bcur[i], cc);
    }
    __syncthreads();
    for (int i = base + t; i < end; i += 256) {
        int col = cols[i];
        int b = col >> BKT_SHIFT;
        int pos = atomicAdd(&c[b], 1);
        stage[pos] = ((uint32)rows[i] << BKT_SHIFT) | (uint32)(col & (BKT_NODES - 1));
    }
}

__global__ __launch_bounds__(256) void bucket_sort_kernel(
    const uint32* __restrict__ stage, const int* __restrict__ bstart,
    int* __restrict__ rowstart, float* __restrict__ dis,
    int* __restrict__ csr, int n, int e) {
    __shared__ int cnt[BKT_NODES];
    __shared__ int excl[BKT_NODES];
    __shared__ int lcur[BKT_NODES];
    int b = blockIdx.x, t = threadIdx.x;
    int s0 = bstart[b], s1 = bstart[b + 1];
    int nnode = min(BKT_NODES, n - b * BKT_NODES);
    if (t < BKT_NODES) cnt[t] = 0;
    __syncthreads();
    for (int i = s0 + t; i < s1; i += 256)
        atomicAdd(&cnt[stage[i] & (BKT_NODES - 1)], 1);
    __syncthreads();
    if (t < BKT_NODES) excl[t] = cnt[t];
    __syncthreads();
    for (int off = 1; off < BKT_NODES; off <<= 1) {
        int x = 0;
        if (t < BKT_NODES && t >= off) x = excl[t - off];
        __syncthreads();
        if (t < BKT_NODES) excl[t] += x;
        __syncthreads();
    }
    if (t < BKT_NODES) {
        int rs = s0 + excl[t] - cnt[t];
        lcur[t] = rs;
        if (t < nnode) {
            rowstart[b * BKT_NODES + t] = rs;
            dis[b * BKT_NODES + t] = rsqrtf((float)(cnt[t] + 1));
        }
    }
    if (b == 0 && t == 0) rowstart[n] = e;
    __syncthreads();
    for (int i = s0 + t; i < s1; i += 256) {
        uint32 v = stage[i];
        int pos = atomicAdd(&lcur[v & (BKT_NODES - 1)], 1);
        csr[pos] = (int)(v >> BKT_SHIFT);
    }
}

// ---------------- weight transpose + bf16 convert (one-time) -------------
// w1t[h][k] = bf16(W1[k][h]) : [64][512];  w2t[c][k] = bf16(W2[k][c]) : [16][64]

__global__ void convw_kernel(const float* __restrict__ W1,
                             const float* __restrict__ W2,
                             unsigned short* __restrict__ w1t,
                             unsigned short* __restrict__ w2t) {
    int i = blockIdx.x * blockDim.x + threadIdx.x;
    if (i < HD * F_IN) {
        int h = i >> 9, k = i & 511;
        w1t[i] = f2bf(W1[k * HD + h]);
    } else {
        int j = i - HD * F_IN;
        if (j < CD * HD) {
            int c = j >> 6, k = j & 63;
            w2t[j] = f2bf(W2[k * CD + c]);
        }
    }
}

// ---------------- MFMA MLP + riemann + init ------------------------------
// block = 256 (4 waves), 64 rows/block. GEMM1 via mfma_f32_16x16x32_bf16:
// wave w owns rows [w*16, w*16+16), computes all 64 h-cols (4 N-frags).
// x and W1^T staged per-64-K-chunk in LDS (bf16, stride 72 = bank rotate).
// GEMM2 (64->16) via LDS round-trip + 2 more MFMA. Epilogue: bias, relu,
// riemann (shfl over the 16 col-lanes of the D layout), hidden/g0 writes.

#define LSTR 72

__global__ __launch_bounds__(256) void mlp_kernel(
    const float* __restrict__ x, const unsigned short* __restrict__ w1t,
    const float* __restrict__ b1, const unsigned short* __restrict__ w2t,
    const float* __restrict__ b2, const float* __restrict__ dis,
    const float* __restrict__ temp, const float* __restrict__ wfn,
    unsigned short* __restrict__ g0, float* __restrict__ hidden, int n) {
    __shared__ __align__(16) unsigned short xb[64 * LSTR];
    __shared__ __align__(16) unsigned short w1b[64 * LSTR];
    __shared__ __align__(16) unsigned short w2b[16 * LSTR];

    const int t = threadIdx.x;
    const int row0 = blockIdx.x * 64;
    const int wave = t >> 6, lane = t & 63;
    const int l15 = lane & 15, lq = lane >> 4;
    const int lrow = (wave << 4) + l15;          // LDS-local A row

    // stage W2^T once (16 x 64 bf16)
    if (t < 128) {
        int cr = t >> 3, part = t & 7;
        *(short8v*)&w2b[cr * LSTR + part * 8] =
            *(const short8v*)&w2t[cr * HD + part * 8];
    }

    float4v acc[4];
#pragma unroll
    for (int i = 0; i < 4; ++i) acc[i] = (float4v)0.0f;

    const int srow = t >> 2, spart = t & 3;      // staging coords
    for (int c = 0; c < F_IN / 64; ++c) {
        __syncthreads();
        {
            int gr = row0 + srow; if (gr >= n) gr = n - 1;
            const float* xp = x + (long)gr * F_IN + c * 64 + spart * 16;
            float4 v0 = *(const float4*)(xp + 0);
            float4 v1 = *(const float4*)(xp + 4);
            float4 v2 = *(const float4*)(xp + 8);
            float4 v3 = *(const float4*)(xp + 12);
            short8v o0, o1;
            o0[0] = (short)f2bf(v0.x); o0[1] = (short)f2bf(v0.y);
            o0[2] = (short)f2bf(v0.z); o0[3] = (short)f2bf(v0.w);
            o0[4] = (short)f2bf(v1.x); o0[5] = (short)f2bf(v1.y);
            o0[6] = (short)f2bf(v1.z); o0[7] = (short)f2bf(v1.w);
            o1[0] = (short)f2bf(v2.x); o1[1] = (short)f2bf(v2.y);
            o1[2] = (short)f2bf(v2.z); o1[3] = (short)f2bf(v2.w);
            o1[4] = (short)f2bf(v3.x); o1[5] = (short)f2bf(v3.y);
            o1[6] = (short)f2bf(v3.z); o1[7] = (short)f2bf(v3.w);
            *(short8v*)&xb[srow * LSTR + spart * 16] = o0;
            *(short8v*)&xb[srow * LSTR + spart * 16 + 8] = o1;
            // W1^T slice: rows h = srow, k-window
            const unsigned short* wp = w1t + srow * F_IN + c * 64 + spart * 16;
            *(short8v*)&w1b[srow * LSTR + spart * 16] = *(const short8v*)(wp);
            *(short8v*)&w1b[srow * LSTR + spart * 16 + 8] = *(const short8v*)(wp + 8);
        }
        __syncthreads();
#pragma unroll
        for (int st = 0; st < 2; ++st) {
            int kb = st * 32 + lq * 8;
            short8v av = *(const short8v*)&xb[lrow * LSTR + kb];
#pragma unroll
            for (int hf = 0; hf < 4; ++hf) {
                short8v bv = *(const short8v*)&w1b[(hf * 16 + l15) * LSTR + kb];
                acc[hf] = __builtin_amdgcn_mfma_f32_16x16x32_bf16(av, bv, acc[hf], 0, 0, 0);
            }
        }
    }

    // bias + relu -> hs (reuse xb), bf16
    __syncthreads();
    {
        int drow = (wave << 4) + (lq << 2);
#pragma unroll
        for (int hf = 0; hf < 4; ++hf) {
            int h = hf * 16 + l15;
            float bv = b1[h];
#pragma unroll
            for (int i = 0; i < 4; ++i) {
                float v = acc[hf][i] + bv;
                v = v > 0.0f ? v : 0.0f;
                xb[(drow + i) * LSTR + h] = f2bf(v);
            }
        }
    }
    __syncthreads();

    // GEMM2: 64 -> 16
    float4v acc2 = (float4v)0.0f;
#pragma unroll
    for (int st = 0; st < 2; ++st) {
        int kb = st * 32 + lq * 8;
        short8v av = *(const short8v*)&xb[lrow * LSTR + kb];
        short8v bv = *(const short8v*)&w2b[l15 * LSTR + kb];
        acc2 = __builtin_amdgcn_mfma_f32_16x16x32_bf16(av, bv, acc2, 0, 0, 0);
    }

    // epilogue: bias2 + riemann + writes
    {
        const int cc = l15;                       // class index
        const int drow = (wave << 4) + (lq << 2); // LDS-local row base
        float b2c = b2[cc];
        float wabs = fabsf(wfn[cc]);
        float o[4], p[4];
#pragma unroll
        for (int i = 0; i < 4; ++i) {
            o[i] = acc2[i] + b2c;
            p[i] = o[i] * o[i] * wabs;
        }
#pragma unroll
        for (int off = 1; off < 16; off <<= 1) {
#pragma unroll
            for (int i = 0; i < 4; ++i) p[i] += __shfl_xor(p[i], off);
        }
        float t0 = temp[0];
#pragma unroll
        for (int i = 0; i < 4; ++i) {
            int grow = row0 + drow + i;
            if (grow < n) {
                float inv = 1.0f / (sqrtf(p[i] + 0.01f) + 0.01f);
                float hn = o[i] * inv;
                float d = dis[grow];
                hidden[(long)grow * CD + cc] = t0 * hn;
                g0[(long)grow * CD + cc] = f2bf(d * hn);
            }
        }
    }
}

// ---------------- fused hop: wave/node, 16 edge-slots x 4 feat-lanes -----

__global__ __launch_bounds__(256) void hop_kernel(
    const unsigned short* __restrict__ g, unsigned short* __restrict__ gn,
    float* __restrict__ hidden, const float* __restrict__ dis,
    const int* __restrict__ rowstart, const int* __restrict__ csr,
    const float* __restrict__ temp, const float* __restrict__ wfn,
    int kidx, int writeg, int n) {
    int wid = (blockIdx.x << 2) + (threadIdx.x >> 6);
    if (wid >= n) return;
    int lane = threadIdx.x & 63;
    int slot = lane >> 2, fl = lane & 3;

    int rs0 = rowstart[wid], rs1 = rowstart[wid + 1];
    ushort4 sv = *(const ushort4*)(g + ((long)wid << 4) + (fl << 2));
    float d = dis[wid];
    float4 w = *(const float4*)(wfn + (fl << 2));

    float a0 = 0.f, a1 = 0.f, a2 = 0.f, a3 = 0.f;
    int e = rs0 + slot;
    while (e + 16 < rs1) {
        int s1 = csr[e];
        int s2 = csr[e + 16];
        ushort4 v1 = *(const ushort4*)(g + ((long)s1 << 4) + (fl << 2));
        ushort4 v2 = *(const ushort4*)(g + ((long)s2 << 4) + (fl << 2));
        a0 += bf2f(v1.x); a1 += bf2f(v1.y); a2 += bf2f(v1.z); a3 += bf2f(v1.w);
        a0 += bf2f(v2.x); a1 += bf2f(v2.y); a2 += bf2f(v2.z); a3 += bf2f(v2.w);
        e += 32;
    }
    if (e < rs1) {
        int s1 = csr[e];
        ushort4 v1 = *(const ushort4*)(g + ((long)s1 << 4) + (fl << 2));
        a0 += bf2f(v1.x); a1 += bf2f(v1.y); a2 += bf2f(v1.z); a3 += bf2f(v1.w);
    }

#pragma unroll
    for (int off = 4; off < 64; off <<= 1) {
        a0 += __shfl_xor(a0, off);
        a1 += __shfl_xor(a1, off);
        a2 += __shfl_xor(a2, off);
        a3 += __shfl_xor(a3, off);
    }

    a0 = (a0 + bf2f(sv.x)) * d;
    a1 = (a1 + bf2f(sv.y)) * d;
    a2 = (a2 + bf2f(sv.z)) * d;
    a3 = (a3 + bf2f(sv.w)) * d;

    float p = a0 * a0 * fabsf(w.x) + a1 * a1 * fabsf(w.y) +
              a2 * a2 * fabsf(w.z) + a3 * a3 * fabsf(w.w);
    p += __shfl_xor(p, 1);
    p += __shfl_xor(p, 2);
    float inv = 1.0f / (sqrtf(p + 0.01f) + 0.01f);
    float h0 = a0 * inv, h1 = a1 * inv, h2 = a2 * inv, h3 = a3 * inv;

    if (slot == 0) {
        float tk = temp[kidx];
        long base = ((long)wid << 4) + (fl << 2);
        float4* hp = (float4*)(hidden + base);
        float4 hv = *hp;
        hv.x = fmaf(tk, h0, hv.x);
        hv.y = fmaf(tk, h1, hv.y);
        hv.z = fmaf(tk, h2, hv.z);
        hv.w = fmaf(tk, h3, hv.w);
        *hp = hv;
        if (writeg) {
            ushort4 o;
            o.x = f2bf(d * h0); o.y = f2bf(d * h1);
            o.z = f2bf(d * h2); o.w = f2bf(d * h3);
            *(ushort4*)(gn + base) = o;
        }
    }
}

// ---------------- launch ----------------

static inline long align4up(long w) { return (w + 3) & ~3L; }

extern "C" void kernel_launch(void* const* d_in, const int* in_sizes, int n_in,
                              void* d_out, int out_size, void* d_ws, size_t ws_size,
                              hipStream_t stream) {
    const float* x          = (const float*)d_in[0];
    const int*   edge_index = (const int*)d_in[1];
    const float* W1         = (const float*)d_in[2];
    const float* b1         = (const float*)d_in[3];
    const float* W2         = (const float*)d_in[4];
    const float* b2         = (const float*)d_in[5];
    const float* temp       = (const float*)d_in[6];
    const float* w_for_norm = (const float*)d_in[7];
    float* hidden = (float*)d_out;

    const int n = in_sizes[0] / F_IN;
    const int e = in_sizes[1] / 2;
    const int* rows = edge_index;        // sources
    const int* cols = edge_index + e;    // destinations
    const int nb = (n + BKT_NODES - 1) / BKT_NODES;

    long off = 0;
    int* wsI = (int*)d_ws;
    int* bcnt      = wsI + off; off = align4up(off + NBKT_MAX);
    int* bstart    = wsI + off; off = align4up(off + NBKT_MAX + 1);
    int* bcur      = wsI + off; off = align4up(off + NBKT_MAX);
    int* rowstart  = wsI + off; off = align4up(off + n + 1);
    float* dis     = (float*)(wsI + off); off = align4up(off + n);
    uint32* stage  = (uint32*)(wsI + off); off = align4up(off + e);
    int* csr       = wsI + off; off = align4up(off + e);
    unsigned short* w1t = (unsigned short*)(wsI + off); off = align4up(off + HD * F_IN / 2);
    unsigned short* w2t = (unsigned short*)(wsI + off); off = align4up(off + CD * HD / 2);
    unsigned short* gA  = (unsigned short*)(wsI + off); off = align4up(off + n * 8);
    unsigned short* gB  = (unsigned short*)(wsI + off); off = align4up(off + n * 8);

    const int B = 256;
    const int nbC = (e + EPB - 1) / EPB;

    zero_kernel<<<(nb + B - 1) / B, B, 0, stream>>>(bcnt, nb);
    bucket_hist_kernel<<<nbC, B, 0, stream>>>(cols, bcnt, e, nb);
    bucket_scan_kernel<<<1, B, 0, stream>>>(bcnt, bstart, bcur, nb);
    scatter_bin_kernel<<<nbC, B, 0, stream>>>(rows, cols, bcur, stage, e, nb);
    bucket_sort_kernel<<<nb, B, 0, stream>>>(stage, bstart, rowstart, dis, csr, n, e);
    convw_kernel<<<(HD * F_IN + CD * HD + B - 1) / B, B, 0, stream>>>(W1, W2, w1t, w2t);

    mlp_kernel<<<(n + 63) / 64, B, 0, stream>>>(x, w1t, b1, w2t, b2, dis, temp,
                                                w_for_norm, gA, hidden, n);

    unsigned short* gsrc = gA;
    unsigned short* gdst = gB;
    for (int k = 1; k <= K_HOPS; ++k) {
        hop_kernel<<<(n + 3) / 4, B, 0, stream>>>(
            gsrc, gdst, hidden, dis, rowstart, csr, temp, w_for_norm,
            k, (k < K_HOPS) ? 1 : 0, n);
        unsigned short* tmp = gsrc; gsrc = gdst; gdst = tmp;
    }
}

// Round 7
// 516.919 us; speedup vs baseline: 5.7419x; 1.0847x over previous
//
#include <hip/hip_runtime.h>
#include <math.h>

#define F_IN 512
#define HD 64
#define CD 16
#define K_HOPS 10

#define BKT_SHIFT 7
#define BKT_NODES 128
#define NBKT_MAX 1024
#define EPB 8192

#define HOP_BLOCKS 2048

typedef unsigned int uint32;
typedef __attribute__((ext_vector_type(8))) short short8v;
typedef __attribute__((ext_vector_type(4))) float float4v;

static __device__ __forceinline__ float bf2f(unsigned short h) {
    return __uint_as_float(((uint32)h) << 16);
}
static __device__ __forceinline__ unsigned short f2bf(float x) {
    uint32 u = __float_as_uint(x);
    u = (u + 0x7FFFu + ((u >> 16) & 1u)) >> 16;   // RNE
    return (unsigned short)u;
}

// ---------------- CSR build: two-level bucket sort ----------------

__global__ void zero_kernel(int* __restrict__ p, int n) {
    int i = blockIdx.x * blockDim.x + threadIdx.x;
    if (i < n) p[i] = 0;
}

__global__ __launch_bounds__(256) void bucket_hist_kernel(
    const int* __restrict__ cols, int* __restrict__ bcnt, int e, int nb) {
    __shared__ int c[NBKT_MAX];
    int t = threadIdx.x;
    for (int i = t; i < nb; i += 256) c[i] = 0;
    __syncthreads();
    int base = blockIdx.x * EPB;
    int end = min(base + EPB, e);
    for (int i = base + t; i < end; i += 256)
        atomicAdd(&c[cols[i] >> BKT_SHIFT], 1);
    __syncthreads();
    for (int i = t; i < nb; i += 256)
        if (c[i]) atomicAdd(&bcnt[i], c[i]);
}

__global__ __launch_bounds__(256) void bucket_scan_kernel(
    const int* __restrict__ bcnt, int* __restrict__ bstart,
    int* __restrict__ bcur, int nb) {
    __shared__ int s[256];
    int t = threadIdx.x;
    int v[4]; int sum = 0;
#pragma unroll
    for (int i = 0; i < 4; ++i) {
        int idx = t * 4 + i;
        v[i] = (idx < nb) ? bcnt[idx] : 0;
        sum += v[i];
    }
    s[t] = sum; __syncthreads();
    for (int off = 1; off < 256; off <<= 1) {
        int x = (t >= off) ? s[t - off] : 0;
        __syncthreads();
        s[t] += x;
        __syncthreads();
    }
    int excl = s[t] - sum;
#pragma unroll
    for (int i = 0; i < 4; ++i) {
        int idx = t * 4 + i;
        if (idx < nb) { bstart[idx] = excl; bcur[idx] = excl; }
        excl += v[i];
    }
    if (t == 255) bstart[nb] = excl;
}

__global__ __launch_bounds__(256) void scatter_bin_kernel(
    const int* __restrict__ rows, const int* __restrict__ cols,
    int* __restrict__ bcur, uint32* __restrict__ stage, int e, int nb) {
    __shared__ int c[NBKT_MAX];
    int t = threadIdx.x;
    for (int i = t; i < nb; i += 256) c[i] = 0;
    __syncthreads();
    int base = blockIdx.x * EPB;
    int end = min(base + EPB, e);
    for (int i = base + t; i < end; i += 256)
        atomicAdd(&c[cols[i] >> BKT_SHIFT], 1);
    __syncthreads();
    for (int i = t; i < nb; i += 256) {
        int cc = c[i];
        if (cc) c[i] = atomicAdd(&bcur[i], cc);
    }
    __syncthreads();
    for (int i = base + t; i < end; i += 256) {
        int col = cols[i];
        int b = col >> BKT_SHIFT;
        int pos = atomicAdd(&c[b], 1);
        stage[pos] = ((uint32)rows[i] << BKT_SHIFT) | (uint32)(col & (BKT_NODES - 1));
    }
}

__global__ __launch_bounds__(256) void bucket_sort_kernel(
    const uint32* __restrict__ stage, const int* __restrict__ bstart,
    int* __restrict__ rowstart, float* __restrict__ dis,
    int* __restrict__ csr, int n, int e) {
    __shared__ int cnt[BKT_NODES];
    __shared__ int excl[BKT_NODES];
    __shared__ int lcur[BKT_NODES];
    int b = blockIdx.x, t = threadIdx.x;
    int s0 = bstart[b], s1 = bstart[b + 1];
    int nnode = min(BKT_NODES, n - b * BKT_NODES);
    if (t < BKT_NODES) cnt[t] = 0;
    __syncthreads();
    for (int i = s0 + t; i < s1; i += 256)
        atomicAdd(&cnt[stage[i] & (BKT_NODES - 1)], 1);
    __syncthreads();
    if (t < BKT_NODES) excl[t] = cnt[t];
    __syncthreads();
    for (int off = 1; off < BKT_NODES; off <<= 1) {
        int x = 0;
        if (t < BKT_NODES && t >= off) x = excl[t - off];
        __syncthreads();
        if (t < BKT_NODES) excl[t] += x;
        __syncthreads();
    }
    if (t < BKT_NODES) {
        int rs = s0 + excl[t] - cnt[t];
        lcur[t] = rs;
        if (t < nnode) {
            rowstart[b * BKT_NODES + t] = rs;
            dis[b * BKT_NODES + t] = rsqrtf((float)(cnt[t] + 1));
        }
    }
    if (b == 0 && t == 0) rowstart[n] = e;
    __syncthreads();
    for (int i = s0 + t; i < s1; i += 256) {
        uint32 v = stage[i];
        int pos = atomicAdd(&lcur[v & (BKT_NODES - 1)], 1);
        csr[pos] = (int)(v >> BKT_SHIFT);
    }
}

// ---------------- weight transpose + bf16 convert (one-time) -------------

__global__ void convw_kernel(const float* __restrict__ W1,
                             const float* __restrict__ W2,
                             unsigned short* __restrict__ w1t,
                             unsigned short* __restrict__ w2t) {
    int i = blockIdx.x * blockDim.x + threadIdx.x;
    if (i < HD * F_IN) {
        int h = i >> 9, k = i & 511;
        w1t[i] = f2bf(W1[k * HD + h]);
    } else {
        int j = i - HD * F_IN;
        if (j < CD * HD) {
            int c = j >> 6, k = j & 63;
            w2t[j] = f2bf(W2[k * CD + c]);
        }
    }
}

// ---------------- MFMA MLP + riemann + init ------------------------------

#define LSTR 72

__global__ __launch_bounds__(256) void mlp_kernel(
    const float* __restrict__ x, const unsigned short* __restrict__ w1t,
    const float* __restrict__ b1, const unsigned short* __restrict__ w2t,
    const float* __restrict__ b2, const float* __restrict__ dis,
    const float* __restrict__ temp, const float* __restrict__ wfn,
    unsigned short* __restrict__ g0, float* __restrict__ hidden, int n) {
    __shared__ __align__(16) unsigned short xb[64 * LSTR];
    __shared__ __align__(16) unsigned short w1b[64 * LSTR];
    __shared__ __align__(16) unsigned short w2b[16 * LSTR];

    const int t = threadIdx.x;
    const int row0 = blockIdx.x * 64;
    const int wave = t >> 6, lane = t & 63;
    const int l15 = lane & 15, lq = lane >> 4;
    const int lrow = (wave << 4) + l15;

    if (t < 128) {
        int cr = t >> 3, part = t & 7;
        *(short8v*)&w2b[cr * LSTR + part * 8] =
            *(const short8v*)&w2t[cr * HD + part * 8];
    }

    float4v acc[4];
#pragma unroll
    for (int i = 0; i < 4; ++i) acc[i] = (float4v)0.0f;

    const int srow = t >> 2, spart = t & 3;
    for (int c = 0; c < F_IN / 64; ++c) {
        __syncthreads();
        {
            int gr = row0 + srow; if (gr >= n) gr = n - 1;
            const float* xp = x + (long)gr * F_IN + c * 64 + spart * 16;
            float4 v0 = *(const float4*)(xp + 0);
            float4 v1 = *(const float4*)(xp + 4);
            float4 v2 = *(const float4*)(xp + 8);
            float4 v3 = *(const float4*)(xp + 12);
            short8v o0, o1;
            o0[0] = (short)f2bf(v0.x); o0[1] = (short)f2bf(v0.y);
            o0[2] = (short)f2bf(v0.z); o0[3] = (short)f2bf(v0.w);
            o0[4] = (short)f2bf(v1.x); o0[5] = (short)f2bf(v1.y);
            o0[6] = (short)f2bf(v1.z); o0[7] = (short)f2bf(v1.w);
            o1[0] = (short)f2bf(v2.x); o1[1] = (short)f2bf(v2.y);
            o1[2] = (short)f2bf(v2.z); o1[3] = (short)f2bf(v2.w);
            o1[4] = (short)f2bf(v3.x); o1[5] = (short)f2bf(v3.y);
            o1[6] = (short)f2bf(v3.z); o1[7] = (short)f2bf(v3.w);
            *(short8v*)&xb[srow * LSTR + spart * 16] = o0;
            *(short8v*)&xb[srow * LSTR + spart * 16 + 8] = o1;
            const unsigned short* wp = w1t + srow * F_IN + c * 64 + spart * 16;
            *(short8v*)&w1b[srow * LSTR + spart * 16] = *(const short8v*)(wp);
            *(short8v*)&w1b[srow * LSTR + spart * 16 + 8] = *(const short8v*)(wp + 8);
        }
        __syncthreads();
#pragma unroll
        for (int st = 0; st < 2; ++st) {
            int kb = st * 32 + lq * 8;
            short8v av = *(const short8v*)&xb[lrow * LSTR + kb];
#pragma unroll
            for (int hf = 0; hf < 4; ++hf) {
                short8v bv = *(const short8v*)&w1b[(hf * 16 + l15) * LSTR + kb];
                acc[hf] = __builtin_amdgcn_mfma_f32_16x16x32_bf16(av, bv, acc[hf], 0, 0, 0);
            }
        }
    }

    __syncthreads();
    {
        int drow = (wave << 4) + (lq << 2);
#pragma unroll
        for (int hf = 0; hf < 4; ++hf) {
            int h = hf * 16 + l15;
            float bv = b1[h];
#pragma unroll
            for (int i = 0; i < 4; ++i) {
                float v = acc[hf][i] + bv;
                v = v > 0.0f ? v : 0.0f;
                xb[(drow + i) * LSTR + h] = f2bf(v);
            }
        }
    }
    __syncthreads();

    float4v acc2 = (float4v)0.0f;
#pragma unroll
    for (int st = 0; st < 2; ++st) {
        int kb = st * 32 + lq * 8;
        short8v av = *(const short8v*)&xb[lrow * LSTR + kb];
        short8v bv = *(const short8v*)&w2b[l15 * LSTR + kb];
        acc2 = __builtin_amdgcn_mfma_f32_16x16x32_bf16(av, bv, acc2, 0, 0, 0);
    }

    {
        const int cc = l15;
        const int drow = (wave << 4) + (lq << 2);
        float b2c = b2[cc];
        float wabs = fabsf(wfn[cc]);
        float o[4], p[4];
#pragma unroll
        for (int i = 0; i < 4; ++i) {
            o[i] = acc2[i] + b2c;
            p[i] = o[i] * o[i] * wabs;
        }
#pragma unroll
        for (int off = 1; off < 16; off <<= 1) {
#pragma unroll
            for (int i = 0; i < 4; ++i) p[i] += __shfl_xor(p[i], off);
        }
        float t0 = temp[0];
#pragma unroll
        for (int i = 0; i < 4; ++i) {
            int grow = row0 + drow + i;
            if (grow < n) {
                float inv = 1.0f / (sqrtf(p[i] + 0.01f) + 0.01f);
                float hn = o[i] * inv;
                float d = dis[grow];
                hidden[(long)grow * CD + cc] = t0 * hn;
                g0[(long)grow * CD + cc] = f2bf(d * hn);
            }
        }
    }
}

// ---------------- fused hop: grid-stride, node-pipelined -----------------
// 8192 waves (32/CU), ~12 nodes each; node = sweep*NW + wave keeps active
// waves on consecutive nodes (csr L2 window ~1MB). Depth-1 software
// pipeline: next node's rowstart/dis/self/hidden AND first-32-edge csr
// indices are in flight while the current node gathers/reduces.

__global__ __launch_bounds__(256) void hop_kernel(
    const unsigned short* __restrict__ g, unsigned short* __restrict__ gn,
    float* __restrict__ hidden, const float* __restrict__ dis,
    const int* __restrict__ rowstart, const int* __restrict__ csr,
    const float* __restrict__ temp, const float* __restrict__ wfn,
    int kidx, int writeg, int n, int etot) {
    const int wv = (blockIdx.x << 2) + (threadIdx.x >> 6);
    const int NW = gridDim.x << 2;
    if (wv >= n) return;
    const int lane = threadIdx.x & 63;
    const int slot = lane >> 2, fl = lane & 3;
    const float4 wq = *(const float4*)(wfn + (fl << 2));
    const float wx = fabsf(wq.x), wy = fabsf(wq.y),
                wz = fabsf(wq.z), ww = fabsf(wq.w);
    const float tk = temp[kidx];

    // prologue: state for first node
    int node = wv;
    int rs0 = rowstart[node], rs1 = rowstart[node + 1];
    float d = dis[node];
    ushort4 sv = *(const ushort4*)(g + ((long)node << 4) + (fl << 2));
    float4 hv;
    if (slot == 0) hv = *(const float4*)(hidden + ((long)node << 4) + (fl << 2));
    int c0 = csr[min(rs0 + slot, etot - 1)];
    int c1 = csr[min(rs0 + slot + 16, etot - 1)];

    for (;;) {
        const int nnext = node + NW;
        const bool has_next = nnext < n;

        // (1) issue next node's independent loads
        int rs0n, rs1n; float dn; ushort4 svn; float4 hvn;
        if (has_next) {
            rs0n = rowstart[nnext];
            rs1n = rowstart[nnext + 1];
            dn = dis[nnext];
            svn = *(const ushort4*)(g + ((long)nnext << 4) + (fl << 2));
            if (slot == 0)
                hvn = *(const float4*)(hidden + ((long)nnext << 4) + (fl << 2));
        }

        // (2) gather current node (first 32 edges via prefetched c0/c1)
        float a0 = 0.f, a1 = 0.f, a2 = 0.f, a3 = 0.f;
        if (rs0 + slot < rs1) {
            ushort4 v1 = *(const ushort4*)(g + ((long)c0 << 4) + (fl << 2));
            a0 += bf2f(v1.x); a1 += bf2f(v1.y); a2 += bf2f(v1.z); a3 += bf2f(v1.w);
        }
        if (rs0 + slot + 16 < rs1) {
            ushort4 v2 = *(const ushort4*)(g + ((long)c1 << 4) + (fl << 2));
            a0 += bf2f(v2.x); a1 += bf2f(v2.y); a2 += bf2f(v2.z); a3 += bf2f(v2.w);
        }
        for (int e2 = rs0 + slot + 32; e2 < rs1; e2 += 16) {
            int s1 = csr[e2];
            ushort4 v = *(const ushort4*)(g + ((long)s1 << 4) + (fl << 2));
            a0 += bf2f(v.x); a1 += bf2f(v.y); a2 += bf2f(v.z); a3 += bf2f(v.w);
        }

        // (3) reduce + riemann + writes
#pragma unroll
        for (int off = 4; off < 64; off <<= 1) {
            a0 += __shfl_xor(a0, off);
            a1 += __shfl_xor(a1, off);
            a2 += __shfl_xor(a2, off);
            a3 += __shfl_xor(a3, off);
        }
        a0 = (a0 + bf2f(sv.x)) * d;
        a1 = (a1 + bf2f(sv.y)) * d;
        a2 = (a2 + bf2f(sv.z)) * d;
        a3 = (a3 + bf2f(sv.w)) * d;
        float p = a0 * a0 * wx + a1 * a1 * wy + a2 * a2 * wz + a3 * a3 * ww;
        p += __shfl_xor(p, 1);
        p += __shfl_xor(p, 2);
        float inv = 1.0f / (sqrtf(p + 0.01f) + 0.01f);
        float h0 = a0 * inv, h1 = a1 * inv, h2 = a2 * inv, h3 = a3 * inv;
        if (slot == 0) {
            long base = ((long)node << 4) + (fl << 2);
            hv.x = fmaf(tk, h0, hv.x);
            hv.y = fmaf(tk, h1, hv.y);
            hv.z = fmaf(tk, h2, hv.z);
            hv.w = fmaf(tk, h3, hv.w);
            *(float4*)(hidden + base) = hv;
            if (writeg) {
                ushort4 o;
                o.x = f2bf(d * h0); o.y = f2bf(d * h1);
                o.z = f2bf(d * h2); o.w = f2bf(d * h3);
                *(ushort4*)(gn + base) = o;
            }
        }

        if (!has_next) break;

        // (4) prefetch next node's first-32-edge csr indices
        int c0n = csr[min(rs0n + slot, etot - 1)];
        int c1n = csr[min(rs0n + slot + 16, etot - 1)];

        // (5) rotate
        node = nnext;
        rs0 = rs0n; rs1 = rs1n; d = dn; sv = svn; hv = hvn;
        c0 = c0n; c1 = c1n;
    }
}

// ---------------- launch ----------------

static inline long align4up(long w) { return (w + 3) & ~3L; }

extern "C" void kernel_launch(void* const* d_in, const int* in_sizes, int n_in,
                              void* d_out, int out_size, void* d_ws, size_t ws_size,
                              hipStream_t stream) {
    const float* x          = (const float*)d_in[0];
    const int*   edge_index = (const int*)d_in[1];
    const float* W1         = (const float*)d_in[2];
    const float* b1         = (const float*)d_in[3];
    const float* W2         = (const float*)d_in[4];
    const float* b2         = (const float*)d_in[5];
    const float* temp       = (const float*)d_in[6];
    const float* w_for_norm = (const float*)d_in[7];
    float* hidden = (float*)d_out;

    const int n = in_sizes[0] / F_IN;
    const int e = in_sizes[1] / 2;
    const int* rows = edge_index;        // sources
    const int* cols = edge_index + e;    // destinations
    const int nb = (n + BKT_NODES - 1) / BKT_NODES;

    long off = 0;
    int* wsI = (int*)d_ws;
    int* bcnt      = wsI + off; off = align4up(off + NBKT_MAX);
    int* bstart    = wsI + off; off = align4up(off + NBKT_MAX + 1);
    int* bcur      = wsI + off; off = align4up(off + NBKT_MAX);
    int* rowstart  = wsI + off; off = align4up(off + n + 1);
    float* dis     = (float*)(wsI + off); off = align4up(off + n);
    uint32* stage  = (uint32*)(wsI + off); off = align4up(off + e);
    int* csr       = wsI + off; off = align4up(off + e);
    unsigned short* w1t = (unsigned short*)(wsI + off); off = align4up(off + HD * F_IN / 2);
    unsigned short* w2t = (unsigned short*)(wsI + off); off = align4up(off + CD * HD / 2);
    unsigned short* gA  = (unsigned short*)(wsI + off); off = align4up(off + n * 8);
    unsigned short* gB  = (unsigned short*)(wsI + off); off = align4up(off + n * 8);

    const int B = 256;
    const int nbC = (e + EPB - 1) / EPB;

    zero_kernel<<<(nb + B - 1) / B, B, 0, stream>>>(bcnt, nb);
    bucket_hist_kernel<<<nbC, B, 0, stream>>>(cols, bcnt, e, nb);
    bucket_scan_kernel<<<1, B, 0, stream>>>(bcnt, bstart, bcur, nb);
    scatter_bin_kernel<<<nbC, B, 0, stream>>>(rows, cols, bcur, stage, e, nb);
    bucket_sort_kernel<<<nb, B, 0, stream>>>(stage, bstart, rowstart, dis, csr, n, e);
    convw_kernel<<<(HD * F_IN + CD * HD + B - 1) / B, B, 0, stream>>>(W1, W2, w1t, w2t);

    mlp_kernel<<<(n + 63) / 64, B, 0, stream>>>(x, w1t, b1, w2t, b2, dis, temp,
                                                w_for_norm, gA, hidden, n);

    unsigned short* gsrc = gA;
    unsigned short* gdst = gB;
    for (int k = 1; k <= K_HOPS; ++k) {
        hop_kernel<<<HOP_BLOCKS, B, 0, stream>>>(
            gsrc, gdst, hidden, dis, rowstart, csr, temp, w_for_norm,
            k, (k < K_HOPS) ? 1 : 0, n, e);
        unsigned short* tmp = gsrc; gsrc = gdst; gdst = tmp;
    }
}